// Round 5
// baseline (195.331 us; speedup 1.0000x reference)
//
#include <hip/hip_runtime.h>
#include <hip/hip_bf16.h>

#define B_   8
#define C_   128
#define HW_  16384
#define N_   16
#define EPS_ 1e-7f

typedef unsigned short u16;
typedef __attribute__((ext_vector_type(8))) short s8v;
typedef __attribute__((ext_vector_type(4))) short s4v;
typedef __attribute__((ext_vector_type(4))) float f4v;

__device__ __forceinline__ u16 f2b(float f) {
  union { __hip_bfloat16 b; u16 u; } cv; cv.b = __float2bfloat16(f); return cv.u;
}
__device__ __forceinline__ float b2f(u16 u) {
  union { float f; unsigned int i; } cv; cv.i = ((unsigned int)u) << 16; return cv.f;
}
__device__ __forceinline__ float wredsum(float v) {
#pragma unroll
  for (int o = 32; o > 0; o >>= 1) v += __shfl_xor(v, o, 64);
  return v;
}
__device__ __forceinline__ float wredmax(float v) {
#pragma unroll
  for (int o = 32; o > 0; o >>= 1) v = fmaxf(v, __shfl_xor(v, o, 64));
  return v;
}

// ---------------- Kernel 1: per-batch partial Gram + fused misc -------------
// Round-3 version (proven -2.6 us vs round-0): reg-side sx shuffle reduce +
// MFMA-native coalesced pbuf stores (now nontemporal: pbuf is a 32-MB
// write-once/read-once stream -> keep it out of L2 so x tiles survive).
// NOTE: nontemporal builtins need ext_vector types (f4v), not HIP float4.
#define XS_ 132  // LDS row stride in u16 (264 B)
__global__ __launch_bounds__(512, 4) void k_gram(
    const float* __restrict__ x, float* __restrict__ pbuf, float* __restrict__ psx,
    const float* __restrict__ Wsa, const float* __restrict__ kn,
    const float* __restrict__ Wo, float* __restrict__ u,
    float* __restrict__ loss_out, u16* __restrict__ wo_bf) {
  __shared__ u16 Xb[C_ * XS_];
  const int tid = threadIdx.x;
  const int b = blockIdx.y;

  if (blockIdx.x == 64) {  // ---- misc blocks ----
    if (b == 0) {          // u[r] = column sums of Wsa
      if (tid < C_) {
        float s = 0.f;
        for (int i = 0; i < C_; ++i) s += Wsa[i * C_ + tid];
        u[tid] = s;
      }
    } else if (b == 1) {   // orth loss (first 256 threads compute)
      float* smf = (float*)Xb;          // [0..15]=nrm, [16..23]=per-wave partials
      const int i = tid >> 4, j = tid & 15;
      float s = 0.f;
      if (tid < 256) {
        for (int c = 0; c < C_; ++c) s += kn[i * C_ + c] * kn[j * C_ + c];
        if (i == j) smf[i] = sqrtf(s);
      }
      __syncthreads();
      float l2 = 0.f;
      if (tid < 256) {
        float l = s / (smf[i] * smf[j] + EPS_) - (i == j ? 1.f : 0.f);
        l2 = l * l;
      }
      float wv = wredsum(l2);
      if ((tid & 63) == 0) smf[16 + (tid >> 6)] = wv;
      __syncthreads();
      if (tid == 0) {
        float t = 0.f;
        for (int k = 0; k < 8; ++k) t += smf[16 + k];
        loss_out[0] = 0.1f * logf(t + 1.f);
      }
    } else if (b == 2) {   // Wo -> bf16
#pragma unroll
      for (int j = 0; j < 8; ++j) {
        int f = tid + 512 * j;
        float4 v = ((const float4*)Wo)[f];
        s4v s; s[0] = (short)f2b(v.x); s[1] = (short)f2b(v.y);
        s[2] = (short)f2b(v.z); s[3] = (short)f2b(v.w);
        ((s4v*)wo_bf)[f] = s;
      }
    }
    return;
  }

  const int p0 = blockIdx.x * 256;
  const int lane = tid & 63;
  const int w = tid >> 6;                 // wave 0..7
  const int m = lane & 15, q = lane >> 4;
  const int rb = (w & 3) * 32, cb = (w >> 2) * 64;

  f4v acc[2][4];
#pragma unroll
  for (int a = 0; a < 2; ++a)
#pragma unroll
    for (int c2 = 0; c2 < 4; ++c2) acc[a][c2] = (f4v){0.f, 0.f, 0.f, 0.f};

  const float* xb = x + (size_t)b * C_ * HW_;
  const float* ro = xb + (size_t)(tid >> 5) * HW_ + p0 + 4 * (tid & 31);

  float4 v[8];
#pragma unroll
  for (int j = 0; j < 8; ++j) v[j] = *(const float4*)(ro + (size_t)(16 * j) * HW_);

  float rs[8];
#pragma unroll
  for (int t = 0; t < 2; ++t) {
    // convert + LDS write (rows c = (tid>>5)+16j, cols 4*(tid&31)) + row sums
#pragma unroll
    for (int j = 0; j < 8; ++j) {
      int c = (tid >> 5) + 16 * j;
      s4v s; s[0] = (short)f2b(v[j].x); s[1] = (short)f2b(v[j].y);
      s[2] = (short)f2b(v[j].z); s[3] = (short)f2b(v[j].w);
      *(s4v*)(&Xb[c * XS_ + 4 * (tid & 31)]) = s;
      float rsum = v[j].x + v[j].y + v[j].z + v[j].w;
      if (t == 0) rs[j] = rsum; else rs[j] += rsum;
    }
    __syncthreads();
    if (t == 0) {  // prefetch tile 1 under tile-0 compute
#pragma unroll
      for (int j = 0; j < 8; ++j) v[j] = *(const float4*)(ro + (size_t)(16 * j) * HW_ + 128);
    }
#pragma unroll
    for (int s = 0; s < 4; ++s) {
      const int k0 = 32 * s;
      s8v Af[2], Bf[4];
#pragma unroll
      for (int a = 0; a < 2; ++a)
        Af[a] = *(const s8v*)(&Xb[(rb + 16 * a + m) * XS_ + k0 + 8 * q]);
#pragma unroll
      for (int c2 = 0; c2 < 4; ++c2)
        Bf[c2] = *(const s8v*)(&Xb[(cb + 16 * c2 + m) * XS_ + k0 + 8 * q]);
#pragma unroll
      for (int a = 0; a < 2; ++a)
#pragma unroll
        for (int c2 = 0; c2 < 4; ++c2)
          acc[a][c2] = __builtin_amdgcn_mfma_f32_16x16x32_bf16(Af[a], Bf[c2], acc[a][c2], 0, 0, 0);
    }
    __syncthreads();
  }

  // pbuf in MFMA-native layout: f4v slot (w*8 + a*4 + c2)*64 + lane (nt)
  f4v* pg4 = (f4v*)pbuf + ((size_t)(blockIdx.x * B_ + b) << 12);
#pragma unroll
  for (int a = 0; a < 2; ++a)
#pragma unroll
    for (int c2 = 0; c2 < 4; ++c2)
      __builtin_nontemporal_store(acc[a][c2], &pg4[(w * 8 + a * 4 + c2) * 64 + lane]);

  // sx: 32-lane shuffle reduce (lanes sharing tid>>5 own the same 8 rows)
#pragma unroll
  for (int o = 16; o > 0; o >>= 1)
#pragma unroll
    for (int j = 0; j < 8; ++j) rs[j] += __shfl_xor(rs[j], o, 64);
  if ((tid & 31) == 0) {
#pragma unroll
    for (int j = 0; j < 8; ++j)
      psx[(blockIdx.x * B_ + b) * C_ + (tid >> 5) + 16 * j] = rs[j];
  }
}

// ---------------- reduce 64 partials -> G, sx ------------------------------
// Reads pbuf (nontemporal: read-once stream) in the coalesced native layout;
// decodes (w,j,lane)->(row,col) only for the tiny G scatter (L2-resident).
__global__ __launch_bounds__(128) void k_greduce(const f4v* __restrict__ pbuf4,
                                                 const float* __restrict__ psx,
                                                 float* __restrict__ G,
                                                 float* __restrict__ sx) {
  const int blk = blockIdx.x;
  if (blk < 256) {
    const int gid = blk * 128 + threadIdx.x;  // [0, 32768)
    const int b = gid >> 12, i4 = gid & 4095;
    f4v s = (f4v){0.f, 0.f, 0.f, 0.f};
#pragma unroll 16
    for (int ch = 0; ch < 64; ++ch) {
      f4v p = __builtin_nontemporal_load(&pbuf4[((size_t)(ch * B_ + b) << 12) + i4]);
      s += p;
    }
    const int w = i4 >> 9, j = (i4 >> 6) & 7, lane = i4 & 63;
    const int a = j >> 2, c2 = j & 3, q = lane >> 4, m = lane & 15;
    const int row0 = (w & 3) * 32 + 16 * a + 4 * q;
    const int col = (w >> 2) * 64 + 16 * c2 + m;
    float* Gp = G + b * C_ * C_ + row0 * C_ + col;
    Gp[0] = s.x; Gp[C_] = s.y; Gp[2 * C_] = s.z; Gp[3 * C_] = s.w;
  } else {
    const int tt = (blk - 256) * 128 + threadIdx.x;  // [0, 1024)
    const int b = tt >> 7, c = tt & 127;
    float s = 0.f;
#pragma unroll 16
    for (int ch = 0; ch < 64; ++ch) s += psx[(ch * B_ + b) * C_ + c];
    sx[tt] = s;
  }
}

// ---------------- Kernel 2: per-(batch, column) G-derived quantities --------
__global__ __launch_bounds__(64) void k_cols(
    const float* __restrict__ G, const float* __restrict__ sx,
    const float* __restrict__ Wr, const float* __restrict__ Wsa,
    const float* __restrict__ Wo, const float* __restrict__ kn,
    const float* __restrict__ u,
    float* diagR, float* diagSA, float* colsumSA, float* diagO,
    float* prv, float* psav, float* pov, float* rel, float* diagN, float* ksx) {
  const int b = blockIdx.y;
  const int col = blockIdx.x;
  const int lane = threadIdx.x;
  const float* Gb = G + b * C_ * C_;
  const float4* g0 = (const float4*)(Gb + lane * C_);
  const float4* g1 = (const float4*)(Gb + (64 + lane) * C_);
  const float sx0 = sx[b * C_ + lane], sx1 = sx[b * C_ + 64 + lane];

  if (col < C_) {
    const float4* wr = (const float4*)(Wr + col * C_);
    const float4* wa = (const float4*)(Wsa + col * C_);
    const float4* wo = (const float4*)(Wo + col * C_);
    float t0r = 0, t1r = 0, t0a = 0, t1a = 0, t0o = 0, t1o = 0;
    for (int c = 0; c < 32; ++c) {
      float4 a0 = g0[c], a1 = g1[c];
      float4 vr = wr[c], va = wa[c], vo = wo[c];
      t0r += a0.x * vr.x + a0.y * vr.y + a0.z * vr.z + a0.w * vr.w;
      t1r += a1.x * vr.x + a1.y * vr.y + a1.z * vr.z + a1.w * vr.w;
      t0a += a0.x * va.x + a0.y * va.y + a0.z * va.z + a0.w * va.w;
      t1a += a1.x * va.x + a1.y * va.y + a1.z * va.z + a1.w * va.w;
      t0o += a0.x * vo.x + a0.y * vo.y + a0.z * vo.z + a0.w * vo.w;
      t1o += a1.x * vo.x + a1.y * vo.y + a1.z * vo.z + a1.w * vo.w;
    }
    float wr0 = Wr[col * C_ + lane], wr1 = Wr[col * C_ + 64 + lane];
    float wa0 = Wsa[col * C_ + lane], wa1 = Wsa[col * C_ + 64 + lane];
    float wo0 = Wo[col * C_ + lane], wo1 = Wo[col * C_ + 64 + lane];
    float u0 = u[lane], u1 = u[64 + lane];
    float dR = wredsum(wr0 * t0r + wr1 * t1r);
    float pR = wredsum(wr0 * sx0 + wr1 * sx1);
    float dA = wredsum(wa0 * t0a + wa1 * t1a);
    float cA = wredsum(u0 * t0a + u1 * t1a);
    float pA = wredsum(wa0 * sx0 + wa1 * sx1);
    float dO = wredsum(wo0 * t0o + wo1 * t1o);
    float pO = wredsum(wo0 * sx0 + wo1 * sx1);
    float rl[N_];
#pragma unroll
    for (int n = 0; n < N_; ++n)
      rl[n] = wredsum(kn[n * C_ + lane] * t0r + kn[n * C_ + 64 + lane] * t1r);
    if (lane == 0) {
      diagR[b * C_ + col] = dR;  prv[b * C_ + col] = pR;
      diagSA[b * C_ + col] = dA; colsumSA[b * C_ + col] = cA; psav[b * C_ + col] = pA;
      diagO[b * C_ + col] = dO;  pov[b * C_ + col] = pO;
      for (int n = 0; n < N_; ++n) rel[(b * N_ + n) * C_ + col] = rl[n];
    }
  } else {
    const int n = col - C_;
    const float4* wk = (const float4*)(kn + n * C_);
    float t0 = 0, t1 = 0;
    for (int c = 0; c < 32; ++c) {
      float4 a0 = g0[c], a1 = g1[c], vk = wk[c];
      t0 += a0.x * vk.x + a0.y * vk.y + a0.z * vk.z + a0.w * vk.w;
      t1 += a1.x * vk.x + a1.y * vk.y + a1.z * vk.z + a1.w * vk.w;
    }
    float k0v = kn[n * C_ + lane], k1v = kn[n * C_ + 64 + lane];
    float dN = wredsum(k0v * t0 + k1v * t1);
    float kx = wredsum(k0v * sx0 + k1v * sx1);
    if (lane == 0) { diagN[b * N_ + n] = dN; ksx[b * N_ + n] = kx; }
  }
}

// ---------------- Kernel 3: per-batch assembly -> c1[b,c], c0[b,c] ----------
// Outputs folded epilogue coefficients: c1 = sigma*A, c0 = sigma*(A*bo - B)
__global__ __launch_bounds__(128) void k_asm(
    const float* diagR, const float* diagSA, const float* colsumSA, const float* diagO,
    const float* prv, const float* psav, const float* pov,
    const float* rel, const float* diagN, const float* ksx,
    const float* br, const float* bo, const float* bsa, const float* alpha,
    const float* sigma, float* C1out, float* C0out) {
  const int b = blockIdx.x;
  const int t = threadIdx.x;
  __shared__ float rb2[2];
  __shared__ float att_s[C_][N_ + 1];
  __shared__ float s1_s[C_], s2_s[C_];
  __shared__ float inv_s[N_], fmi_s[N_];
  const float hw = (float)HW_;
  const float bsa_c = bsa[t], br_c = br[t], bo_c = bo[t];
  const float psa_c = psav[b * C_ + t], pr_c = prv[b * C_ + t], po_c = pov[b * C_ + t];

  float bsum, psum, mx, ssum;
  { float wv = wredsum(bsa_c); if ((t & 63) == 0) rb2[t >> 6] = wv; __syncthreads();
    bsum = rb2[0] + rb2[1]; __syncthreads(); }
  { float wv = wredsum(psa_c); if ((t & 63) == 0) rb2[t >> 6] = wv; __syncthreads();
    psum = rb2[0] + rb2[1]; __syncthreads(); }

  const float nxr = sqrtf(fmaxf(diagR[b * C_ + t] + 2.f * br_c * pr_c + hw * br_c * br_c, 0.f));
  s1_s[t] = po_c + hw * bo_c;
  s2_s[t] = diagO[b * C_ + t] + 2.f * bo_c * po_c + hw * bo_c * bo_c;
  const float colsum = colsumSA[b * C_ + t] + bsum * psa_c + bsa_c * (psum + hw * bsum);
  const float diagv = diagSA[b * C_ + t] + 2.f * bsa_c * psa_c + hw * bsa_c * bsa_c;
  const float fm = (colsum - diagv) * (1.f / (float)C_);

  { float wv = wredmax(fm); if ((t & 63) == 0) rb2[t >> 6] = wv; __syncthreads();
    mx = fmaxf(rb2[0], rb2[1]); __syncthreads(); }
  const float ee = expf(fm - mx);
  { float wv = wredsum(ee); if ((t & 63) == 0) rb2[t >> 6] = wv; __syncthreads();
    ssum = rb2[0] + rb2[1]; __syncthreads(); }
  const float reg = ee / ssum;

  float r[N_];
  float rmax = -1e30f;
#pragma unroll
  for (int n = 0; n < N_; ++n) {
    float al = fminf(fmaxf(alpha[n], 0.f), 1.f);
    float nxn = sqrtf(fmaxf(diagN[b * N_ + n], 0.f));
    float rv = (rel[(b * N_ + n) * C_ + t] + br_c * ksx[b * N_ + n]) / (nxn * nxr + EPS_) + al * reg;
    r[n] = rv; rmax = fmaxf(rmax, rv);
  }
  float es = 0.f;
#pragma unroll
  for (int n = 0; n < N_; ++n) { r[n] = expf(r[n] - rmax); es += r[n]; }
  const float ies = 1.f / es;
#pragma unroll
  for (int n = 0; n < N_; ++n) att_s[t][n] = r[n] * ies;
  __syncthreads();

  {
    const int nn = t >> 3, g = t & 7;     // 8 lanes per class n
    float sa = 0.f, sh = 0.f, sq = 0.f;
#pragma unroll 4
    for (int c = g; c < C_; c += 8) {
      float a = att_s[c][nn];
      sa += a; sh += a * s1_s[c]; sq += a * a * s2_s[c];
    }
#pragma unroll
    for (int o = 4; o > 0; o >>= 1) {
      sa += __shfl_xor(sa, o, 64);
      sh += __shfl_xor(sh, o, 64);
      sq += __shfl_xor(sq, o, 64);
    }
    if (g == 0) {
      float cnt = sa * hw + EPS_;
      float fmean = sh / cnt;
      float sqv = sq - 2.f * fmean * sh + fmean * fmean * ((float)C_ * hw);
      float fstd = sqrtf(fmaxf(sqv, 0.f) / cnt);
      float inv = 1.f / (fstd + EPS_);
      inv_s[nn] = inv; fmi_s[nn] = fmean * inv;
    }
  }
  __syncthreads();

  float Ac = 0.f, Bc = 0.f;
#pragma unroll
  for (int n = 0; n < N_; ++n) { float a = att_s[t][n]; Ac += a * inv_s[n]; Bc += a * fmi_s[n]; }
  const float sg = sigma[0];
  C1out[b * C_ + t] = sg * Ac;
  C0out[b * C_ + t] = sg * (Ac * bo_c - Bc);
}

// ---------------- Kernel 4: out = x + c1[c]*(Wo x)[c,p] + c0[c] -------------
// ROUND-0-PROVEN structure (4x64-px passes, pipelined prefetch, 17 KB LDS,
// 2 blocks/CU). Changes vs round-0: folded c1/c0 coefficients; nontemporal
// out-stores (out never re-read -> stop evicting the staged x from L2, which
// round-1 counters showed as FETCH 95 MB vs 64 ideal); nontemporal x re-read.
#define XT_ 132
__global__ __launch_bounds__(512, 4) void k_out(
    const float* __restrict__ x, const u16* __restrict__ wo_bf,
    const float* __restrict__ c1g, const float* __restrict__ c0g,
    float* __restrict__ out) {
  const int b = blockIdx.y;
  __shared__ u16 Xt[64 * XT_];     // 16896 B
  __shared__ float c1s[C_], c0s[C_];
  const int tid = threadIdx.x, lane = tid & 63, w = tid >> 6;  // wave 0..7
  const int n = lane & 15, q = lane >> 4;

  if (tid < C_) { c1s[tid] = c1g[b * C_ + tid]; c0s[tid] = c0g[b * C_ + tid]; }

  // per-wave Wo fragments: af[s] = Wo_bf16[16w+n][32s+8q .. +7]  (16 VGPRs)
  s8v af[4];
#pragma unroll
  for (int s = 0; s < 4; ++s)
    af[s] = *(const s8v*)(wo_bf + (16 * w + n) * C_ + 32 * s + 8 * q);

  const float* xb = x + (size_t)b * C_ * HW_;
  float* ob = out + (size_t)b * C_ * HW_;
  const int pq = tid & 15;           // p-quad 0..15
  const int c4 = tid >> 4;           // c-quad 0..31

  float4 v[4];
  {
    const int p0 = blockIdx.x * 256;
    const float* src = xb + (size_t)(4 * c4) * HW_ + p0 + 4 * pq;
#pragma unroll
    for (int r2 = 0; r2 < 4; ++r2) v[r2] = *(const float4*)(src + (size_t)r2 * HW_);
  }

#pragma unroll 1
  for (int pt = 0; pt < 4; ++pt) {
    const int p0 = blockIdx.x * 256 + pt * 64;
    // transpose + convert + LDS write: cell = 4c x 4p per thread
    {
      float4 v0 = v[0], v1 = v[1], v2 = v[2], v3 = v[3];
      s4v s0, s1, s2, s3;
      s0[0] = (short)f2b(v0.x); s0[1] = (short)f2b(v1.x); s0[2] = (short)f2b(v2.x); s0[3] = (short)f2b(v3.x);
      s1[0] = (short)f2b(v0.y); s1[1] = (short)f2b(v1.y); s1[2] = (short)f2b(v2.y); s1[3] = (short)f2b(v3.y);
      s2[0] = (short)f2b(v0.z); s2[1] = (short)f2b(v1.z); s2[2] = (short)f2b(v2.z); s2[3] = (short)f2b(v3.z);
      s3[0] = (short)f2b(v0.w); s3[1] = (short)f2b(v1.w); s3[2] = (short)f2b(v2.w); s3[3] = (short)f2b(v3.w);
      *(s4v*)(&Xt[(4 * pq + 0) * XT_ + 4 * c4]) = s0;
      *(s4v*)(&Xt[(4 * pq + 1) * XT_ + 4 * c4]) = s1;
      *(s4v*)(&Xt[(4 * pq + 2) * XT_ + 4 * c4]) = s2;
      *(s4v*)(&Xt[(4 * pq + 3) * XT_ + 4 * c4]) = s3;
    }
    __syncthreads();
    if (pt < 3) {  // prefetch next tile under MFMA
      const float* src = xb + (size_t)(4 * c4) * HW_ + p0 + 64 + 4 * pq;
#pragma unroll
      for (int r2 = 0; r2 < 4; ++r2) v[r2] = *(const float4*)(src + (size_t)r2 * HW_);
    }

    f4v acc[4];
#pragma unroll
    for (int p2 = 0; p2 < 4; ++p2) acc[p2] = (f4v){0.f, 0.f, 0.f, 0.f};
#pragma unroll
    for (int s = 0; s < 4; ++s) {
#pragma unroll
      for (int p2 = 0; p2 < 4; ++p2) {
        s8v bfr = *(const s8v*)(&Xt[(16 * p2 + n) * XT_ + 32 * s + 8 * q]);
        acc[p2] = __builtin_amdgcn_mfma_f32_16x16x32_bf16(af[s], bfr, acc[p2], 0, 0, 0);
      }
    }

#pragma unroll
    for (int p2 = 0; p2 < 4; ++p2)
#pragma unroll
      for (int r = 0; r < 4; ++r) {
        int o = 16 * w + 4 * q + r;
        size_t idx = (size_t)o * HW_ + p0 + 16 * p2 + n;
        float xv = __builtin_nontemporal_load(&xb[idx]);
        __builtin_nontemporal_store(xv + c1s[o] * acc[p2][r] + c0s[o], &ob[idx]);
      }
    __syncthreads();
  }
}

extern "C" void kernel_launch(void* const* d_in, const int* in_sizes, int n_in,
                              void* d_out, int out_size, void* d_ws, size_t ws_size,
                              hipStream_t stream) {
  (void)in_sizes; (void)n_in; (void)out_size; (void)ws_size;
  const float* x     = (const float*)d_in[0];
  const float* Wsa   = (const float*)d_in[1];
  const float* bsa   = (const float*)d_in[2];
  const float* Wr    = (const float*)d_in[3];
  const float* br    = (const float*)d_in[4];
  const float* kn    = (const float*)d_in[5];
  const float* Wo    = (const float*)d_in[6];
  const float* bo    = (const float*)d_in[7];
  const float* alpha = (const float*)d_in[8];
  const float* sigma = (const float*)d_in[9];
  float* out = (float*)d_out;
  float* ws  = (float*)d_ws;

  float* G        = ws;            // 131072
  float* sx       = ws + 131072;   // 1024
  float* diagR    = ws + 132096;   // 1024
  float* diagSA   = ws + 133120;   // 1024
  float* colsumSA = ws + 134144;   // 1024
  float* diagO    = ws + 135168;   // 1024
  float* prv      = ws + 136192;   // 1024
  float* psav     = ws + 137216;   // 1024
  float* pov      = ws + 138240;   // 1024
  float* rel      = ws + 139264;   // 16384
  float* diagN    = ws + 155648;   // 128
  float* ksx      = ws + 155776;   // 128
  float* u        = ws + 155904;   // 128
  float* C1w      = ws + 156032;   // 1024
  float* C0w      = ws + 157056;   // 1024
  u16*   wo_bf    = (u16*)(ws + 158080);  // 16384 u16 = 8192 floats

  // d_out doubles as scratch for Gram partials until k_out overwrites it:
  float* pbuf = out;               // 64*8*16384 = 8388608 floats
  float* psx  = out + 8388608;     // 64*8*128   = 65536 floats

  k_gram<<<dim3(65, 8), 512, 0, stream>>>(x, pbuf, psx, Wsa, kn, Wo, u,
      out + (size_t)B_ * C_ * HW_, wo_bf);
  k_greduce<<<264, 128, 0, stream>>>((const f4v*)pbuf, psx, G, sx);
  k_cols<<<dim3(144, 8), 64, 0, stream>>>(G, sx, Wr, Wsa, Wo, kn, u,
      diagR, diagSA, colsumSA, diagO, prv, psav, pov, rel, diagN, ksx);
  k_asm<<<8, 128, 0, stream>>>(diagR, diagSA, colsumSA, diagO, prv, psav, pov,
      rel, diagN, ksx, br, bo, bsa, alpha, sigma, C1w, C0w);
  k_out<<<dim3(64, 8), 512, 0, stream>>>(x, wo_bf, C1w, C0w, out);
}

// Round 6
// 182.652 us; speedup vs baseline: 1.0694x; 1.0694x over previous
//
#include <hip/hip_runtime.h>
#include <hip/hip_bf16.h>

#define B_   8
#define C_   128
#define HW_  16384
#define N_   16
#define EPS_ 1e-7f

typedef unsigned short u16;
typedef __attribute__((ext_vector_type(8))) short s8v;
typedef __attribute__((ext_vector_type(4))) short s4v;
typedef __attribute__((ext_vector_type(4))) float f4v;

__device__ __forceinline__ u16 f2b(float f) {
  union { __hip_bfloat16 b; u16 u; } cv; cv.b = __float2bfloat16(f); return cv.u;
}
__device__ __forceinline__ float b2f(u16 u) {
  union { float f; unsigned int i; } cv; cv.i = ((unsigned int)u) << 16; return cv.f;
}
__device__ __forceinline__ float wredsum(float v) {
#pragma unroll
  for (int o = 32; o > 0; o >>= 1) v += __shfl_xor(v, o, 64);
  return v;
}
__device__ __forceinline__ float wredmax(float v) {
#pragma unroll
  for (int o = 32; o > 0; o >>= 1) v = fmaxf(v, __shfl_xor(v, o, 64));
  return v;
}

// ---------------- Kernel 1: per-batch partial Gram + fused misc -------------
// Round-3 proven version (-2.6 us): reg-side sx shuffle reduce + MFMA-native
// coalesced pbuf stores. NO nontemporal (round-5 lesson: nt = no-allocate
// costs ~15 us total; pbuf wants L2/L3 absorption for k_greduce's read).
#define XS_ 132  // LDS row stride in u16 (264 B)
__global__ __launch_bounds__(512, 4) void k_gram(
    const float* __restrict__ x, float* __restrict__ pbuf, float* __restrict__ psx,
    const float* __restrict__ Wsa, const float* __restrict__ kn,
    const float* __restrict__ Wo, float* __restrict__ u,
    float* __restrict__ loss_out, u16* __restrict__ wo_bf) {
  __shared__ u16 Xb[C_ * XS_];
  const int tid = threadIdx.x;
  const int b = blockIdx.y;

  if (blockIdx.x == 64) {  // ---- misc blocks ----
    if (b == 0) {          // u[r] = column sums of Wsa
      if (tid < C_) {
        float s = 0.f;
        for (int i = 0; i < C_; ++i) s += Wsa[i * C_ + tid];
        u[tid] = s;
      }
    } else if (b == 1) {   // orth loss (first 256 threads compute)
      float* smf = (float*)Xb;          // [0..15]=nrm, [16..23]=per-wave partials
      const int i = tid >> 4, j = tid & 15;
      float s = 0.f;
      if (tid < 256) {
        for (int c = 0; c < C_; ++c) s += kn[i * C_ + c] * kn[j * C_ + c];
        if (i == j) smf[i] = sqrtf(s);
      }
      __syncthreads();
      float l2 = 0.f;
      if (tid < 256) {
        float l = s / (smf[i] * smf[j] + EPS_) - (i == j ? 1.f : 0.f);
        l2 = l * l;
      }
      float wv = wredsum(l2);
      if ((tid & 63) == 0) smf[16 + (tid >> 6)] = wv;
      __syncthreads();
      if (tid == 0) {
        float t = 0.f;
        for (int k = 0; k < 8; ++k) t += smf[16 + k];
        loss_out[0] = 0.1f * logf(t + 1.f);
      }
    } else if (b == 2) {   // Wo -> bf16
#pragma unroll
      for (int j = 0; j < 8; ++j) {
        int f = tid + 512 * j;
        float4 v = ((const float4*)Wo)[f];
        s4v s; s[0] = (short)f2b(v.x); s[1] = (short)f2b(v.y);
        s[2] = (short)f2b(v.z); s[3] = (short)f2b(v.w);
        ((s4v*)wo_bf)[f] = s;
      }
    }
    return;
  }

  const int p0 = blockIdx.x * 256;
  const int lane = tid & 63;
  const int w = tid >> 6;                 // wave 0..7
  const int m = lane & 15, q = lane >> 4;
  const int rb = (w & 3) * 32, cb = (w >> 2) * 64;

  f4v acc[2][4];
#pragma unroll
  for (int a = 0; a < 2; ++a)
#pragma unroll
    for (int c2 = 0; c2 < 4; ++c2) acc[a][c2] = (f4v){0.f, 0.f, 0.f, 0.f};

  const float* xb = x + (size_t)b * C_ * HW_;
  const float* ro = xb + (size_t)(tid >> 5) * HW_ + p0 + 4 * (tid & 31);

  float4 v[8];
#pragma unroll
  for (int j = 0; j < 8; ++j) v[j] = *(const float4*)(ro + (size_t)(16 * j) * HW_);

  float rs[8];
#pragma unroll
  for (int t = 0; t < 2; ++t) {
    // convert + LDS write (rows c = (tid>>5)+16j, cols 4*(tid&31)) + row sums
#pragma unroll
    for (int j = 0; j < 8; ++j) {
      int c = (tid >> 5) + 16 * j;
      s4v s; s[0] = (short)f2b(v[j].x); s[1] = (short)f2b(v[j].y);
      s[2] = (short)f2b(v[j].z); s[3] = (short)f2b(v[j].w);
      *(s4v*)(&Xb[c * XS_ + 4 * (tid & 31)]) = s;
      float rsum = v[j].x + v[j].y + v[j].z + v[j].w;
      if (t == 0) rs[j] = rsum; else rs[j] += rsum;
    }
    __syncthreads();
    if (t == 0) {  // prefetch tile 1 under tile-0 compute
#pragma unroll
      for (int j = 0; j < 8; ++j) v[j] = *(const float4*)(ro + (size_t)(16 * j) * HW_ + 128);
    }
#pragma unroll
    for (int s = 0; s < 4; ++s) {
      const int k0 = 32 * s;
      s8v Af[2], Bf[4];
#pragma unroll
      for (int a = 0; a < 2; ++a)
        Af[a] = *(const s8v*)(&Xb[(rb + 16 * a + m) * XS_ + k0 + 8 * q]);
#pragma unroll
      for (int c2 = 0; c2 < 4; ++c2)
        Bf[c2] = *(const s8v*)(&Xb[(cb + 16 * c2 + m) * XS_ + k0 + 8 * q]);
#pragma unroll
      for (int a = 0; a < 2; ++a)
#pragma unroll
        for (int c2 = 0; c2 < 4; ++c2)
          acc[a][c2] = __builtin_amdgcn_mfma_f32_16x16x32_bf16(Af[a], Bf[c2], acc[a][c2], 0, 0, 0);
    }
    __syncthreads();
  }

  // pbuf in MFMA-native layout: f4v slot (w*8 + a*4 + c2)*64 + lane
  f4v* pg4 = (f4v*)pbuf + ((size_t)(blockIdx.x * B_ + b) << 12);
#pragma unroll
  for (int a = 0; a < 2; ++a)
#pragma unroll
    for (int c2 = 0; c2 < 4; ++c2)
      pg4[(w * 8 + a * 4 + c2) * 64 + lane] = acc[a][c2];

  // sx: 32-lane shuffle reduce (lanes sharing tid>>5 own the same 8 rows)
#pragma unroll
  for (int o = 16; o > 0; o >>= 1)
#pragma unroll
    for (int j = 0; j < 8; ++j) rs[j] += __shfl_xor(rs[j], o, 64);
  if ((tid & 31) == 0) {
#pragma unroll
    for (int j = 0; j < 8; ++j)
      psx[(blockIdx.x * B_ + b) * C_ + (tid >> 5) + 16 * j] = rs[j];
  }
}

// ---------------- reduce 64 partials -> G, sx ------------------------------
// Reads pbuf in the coalesced native layout (plain loads: let L2/L3 serve);
// decodes (w,j,lane)->(row,col) only for the tiny G scatter (L2-resident).
__global__ __launch_bounds__(128) void k_greduce(const f4v* __restrict__ pbuf4,
                                                 const float* __restrict__ psx,
                                                 float* __restrict__ G,
                                                 float* __restrict__ sx) {
  const int blk = blockIdx.x;
  if (blk < 256) {
    const int gid = blk * 128 + threadIdx.x;  // [0, 32768)
    const int b = gid >> 12, i4 = gid & 4095;
    f4v s = (f4v){0.f, 0.f, 0.f, 0.f};
#pragma unroll 16
    for (int ch = 0; ch < 64; ++ch)
      s += pbuf4[((size_t)(ch * B_ + b) << 12) + i4];
    const int w = i4 >> 9, j = (i4 >> 6) & 7, lane = i4 & 63;
    const int a = j >> 2, c2 = j & 3, q = lane >> 4, m = lane & 15;
    const int row0 = (w & 3) * 32 + 16 * a + 4 * q;
    const int col = (w >> 2) * 64 + 16 * c2 + m;
    float* Gp = G + b * C_ * C_ + row0 * C_ + col;
    Gp[0] = s.x; Gp[C_] = s.y; Gp[2 * C_] = s.z; Gp[3 * C_] = s.w;
  } else {
    const int tt = (blk - 256) * 128 + threadIdx.x;  // [0, 1024)
    const int b = tt >> 7, c = tt & 127;
    float s = 0.f;
#pragma unroll 16
    for (int ch = 0; ch < 64; ++ch) s += psx[(ch * B_ + b) * C_ + c];
    sx[tt] = s;
  }
}

// ---------------- Kernel 2: per-(batch, column) G-derived quantities --------
__global__ __launch_bounds__(64) void k_cols(
    const float* __restrict__ G, const float* __restrict__ sx,
    const float* __restrict__ Wr, const float* __restrict__ Wsa,
    const float* __restrict__ Wo, const float* __restrict__ kn,
    const float* __restrict__ u,
    float* diagR, float* diagSA, float* colsumSA, float* diagO,
    float* prv, float* psav, float* pov, float* rel, float* diagN, float* ksx) {
  const int b = blockIdx.y;
  const int col = blockIdx.x;
  const int lane = threadIdx.x;
  const float* Gb = G + b * C_ * C_;
  const float4* g0 = (const float4*)(Gb + lane * C_);
  const float4* g1 = (const float4*)(Gb + (64 + lane) * C_);
  const float sx0 = sx[b * C_ + lane], sx1 = sx[b * C_ + 64 + lane];

  if (col < C_) {
    const float4* wr = (const float4*)(Wr + col * C_);
    const float4* wa = (const float4*)(Wsa + col * C_);
    const float4* wo = (const float4*)(Wo + col * C_);
    float t0r = 0, t1r = 0, t0a = 0, t1a = 0, t0o = 0, t1o = 0;
    for (int c = 0; c < 32; ++c) {
      float4 a0 = g0[c], a1 = g1[c];
      float4 vr = wr[c], va = wa[c], vo = wo[c];
      t0r += a0.x * vr.x + a0.y * vr.y + a0.z * vr.z + a0.w * vr.w;
      t1r += a1.x * vr.x + a1.y * vr.y + a1.z * vr.z + a1.w * vr.w;
      t0a += a0.x * va.x + a0.y * va.y + a0.z * va.z + a0.w * va.w;
      t1a += a1.x * va.x + a1.y * va.y + a1.z * va.z + a1.w * va.w;
      t0o += a0.x * vo.x + a0.y * vo.y + a0.z * vo.z + a0.w * vo.w;
      t1o += a1.x * vo.x + a1.y * vo.y + a1.z * vo.z + a1.w * vo.w;
    }
    float wr0 = Wr[col * C_ + lane], wr1 = Wr[col * C_ + 64 + lane];
    float wa0 = Wsa[col * C_ + lane], wa1 = Wsa[col * C_ + 64 + lane];
    float wo0 = Wo[col * C_ + lane], wo1 = Wo[col * C_ + 64 + lane];
    float u0 = u[lane], u1 = u[64 + lane];
    float dR = wredsum(wr0 * t0r + wr1 * t1r);
    float pR = wredsum(wr0 * sx0 + wr1 * sx1);
    float dA = wredsum(wa0 * t0a + wa1 * t1a);
    float cA = wredsum(u0 * t0a + u1 * t1a);
    float pA = wredsum(wa0 * sx0 + wa1 * sx1);
    float dO = wredsum(wo0 * t0o + wo1 * t1o);
    float pO = wredsum(wo0 * sx0 + wo1 * sx1);
    float rl[N_];
#pragma unroll
    for (int n = 0; n < N_; ++n)
      rl[n] = wredsum(kn[n * C_ + lane] * t0r + kn[n * C_ + 64 + lane] * t1r);
    if (lane == 0) {
      diagR[b * C_ + col] = dR;  prv[b * C_ + col] = pR;
      diagSA[b * C_ + col] = dA; colsumSA[b * C_ + col] = cA; psav[b * C_ + col] = pA;
      diagO[b * C_ + col] = dO;  pov[b * C_ + col] = pO;
      for (int n = 0; n < N_; ++n) rel[(b * N_ + n) * C_ + col] = rl[n];
    }
  } else {
    const int n = col - C_;
    const float4* wk = (const float4*)(kn + n * C_);
    float t0 = 0, t1 = 0;
    for (int c = 0; c < 32; ++c) {
      float4 a0 = g0[c], a1 = g1[c], vk = wk[c];
      t0 += a0.x * vk.x + a0.y * vk.y + a0.z * vk.z + a0.w * vk.w;
      t1 += a1.x * vk.x + a1.y * vk.y + a1.z * vk.z + a1.w * vk.w;
    }
    float k0v = kn[n * C_ + lane], k1v = kn[n * C_ + 64 + lane];
    float dN = wredsum(k0v * t0 + k1v * t1);
    float kx = wredsum(k0v * sx0 + k1v * sx1);
    if (lane == 0) { diagN[b * N_ + n] = dN; ksx[b * N_ + n] = kx; }
  }
}

// ---------------- Kernel 3: per-batch assembly -> c1[b,c], c0[b,c] ----------
// Outputs folded epilogue coefficients: c1 = sigma*A, c0 = sigma*(A*bo - B)
__global__ __launch_bounds__(128) void k_asm(
    const float* diagR, const float* diagSA, const float* colsumSA, const float* diagO,
    const float* prv, const float* psav, const float* pov,
    const float* rel, const float* diagN, const float* ksx,
    const float* br, const float* bo, const float* bsa, const float* alpha,
    const float* sigma, float* C1out, float* C0out) {
  const int b = blockIdx.x;
  const int t = threadIdx.x;
  __shared__ float rb2[2];
  __shared__ float att_s[C_][N_ + 1];
  __shared__ float s1_s[C_], s2_s[C_];
  __shared__ float inv_s[N_], fmi_s[N_];
  const float hw = (float)HW_;
  const float bsa_c = bsa[t], br_c = br[t], bo_c = bo[t];
  const float psa_c = psav[b * C_ + t], pr_c = prv[b * C_ + t], po_c = pov[b * C_ + t];

  float bsum, psum, mx, ssum;
  { float wv = wredsum(bsa_c); if ((t & 63) == 0) rb2[t >> 6] = wv; __syncthreads();
    bsum = rb2[0] + rb2[1]; __syncthreads(); }
  { float wv = wredsum(psa_c); if ((t & 63) == 0) rb2[t >> 6] = wv; __syncthreads();
    psum = rb2[0] + rb2[1]; __syncthreads(); }

  const float nxr = sqrtf(fmaxf(diagR[b * C_ + t] + 2.f * br_c * pr_c + hw * br_c * br_c, 0.f));
  s1_s[t] = po_c + hw * bo_c;
  s2_s[t] = diagO[b * C_ + t] + 2.f * bo_c * po_c + hw * bo_c * bo_c;
  const float colsum = colsumSA[b * C_ + t] + bsum * psa_c + bsa_c * (psum + hw * bsum);
  const float diagv = diagSA[b * C_ + t] + 2.f * bsa_c * psa_c + hw * bsa_c * bsa_c;
  const float fm = (colsum - diagv) * (1.f / (float)C_);

  { float wv = wredmax(fm); if ((t & 63) == 0) rb2[t >> 6] = wv; __syncthreads();
    mx = fmaxf(rb2[0], rb2[1]); __syncthreads(); }
  const float ee = expf(fm - mx);
  { float wv = wredsum(ee); if ((t & 63) == 0) rb2[t >> 6] = wv; __syncthreads();
    ssum = rb2[0] + rb2[1]; __syncthreads(); }
  const float reg = ee / ssum;

  float r[N_];
  float rmax = -1e30f;
#pragma unroll
  for (int n = 0; n < N_; ++n) {
    float al = fminf(fmaxf(alpha[n], 0.f), 1.f);
    float nxn = sqrtf(fmaxf(diagN[b * N_ + n], 0.f));
    float rv = (rel[(b * N_ + n) * C_ + t] + br_c * ksx[b * N_ + n]) / (nxn * nxr + EPS_) + al * reg;
    r[n] = rv; rmax = fmaxf(rmax, rv);
  }
  float es = 0.f;
#pragma unroll
  for (int n = 0; n < N_; ++n) { r[n] = expf(r[n] - rmax); es += r[n]; }
  const float ies = 1.f / es;
#pragma unroll
  for (int n = 0; n < N_; ++n) att_s[t][n] = r[n] * ies;
  __syncthreads();

  {
    const int nn = t >> 3, g = t & 7;     // 8 lanes per class n
    float sa = 0.f, sh = 0.f, sq = 0.f;
#pragma unroll 4
    for (int c = g; c < C_; c += 8) {
      float a = att_s[c][nn];
      sa += a; sh += a * s1_s[c]; sq += a * a * s2_s[c];
    }
#pragma unroll
    for (int o = 4; o > 0; o >>= 1) {
      sa += __shfl_xor(sa, o, 64);
      sh += __shfl_xor(sh, o, 64);
      sq += __shfl_xor(sq, o, 64);
    }
    if (g == 0) {
      float cnt = sa * hw + EPS_;
      float fmean = sh / cnt;
      float sqv = sq - 2.f * fmean * sh + fmean * fmean * ((float)C_ * hw);
      float fstd = sqrtf(fmaxf(sqv, 0.f) / cnt);
      float inv = 1.f / (fstd + EPS_);
      inv_s[nn] = inv; fmi_s[nn] = fmean * inv;
    }
  }
  __syncthreads();

  float Ac = 0.f, Bc = 0.f;
#pragma unroll
  for (int n = 0; n < N_; ++n) { float a = att_s[t][n]; Ac += a * inv_s[n]; Bc += a * fmi_s[n]; }
  const float sg = sigma[0];
  C1out[b * C_ + t] = sg * Ac;
  C0out[b * C_ + t] = sg * (Ac * bo_c - Bc);
}

// ---------------- Kernel 4: out = x + c1[c]*(Wo x)[c,p] + c0[c] -------------
// Round-0-proven inner structure, but 128-px chunks (2 passes) on grid
// (128,8) = 1024 blocks instead of 256-px/4-pass on 512 blocks. v0 was
// GRID-limited to 2 blocks/CU = 16 waves/CU (Occupancy ~36%) while VGPR=64
// and LDS=17 KB permit 8 waves/SIMD; 1024 blocks -> 4 blocks/CU = 32
// waves/CU, doubling latency hiding. Inner code identical. Plain loads/
// stores (round-5: nt forced the epilogue x re-read to HBM, +9.5 us).
#define XT_ 132
__global__ __launch_bounds__(512, 4) void k_out(
    const float* __restrict__ x, const u16* __restrict__ wo_bf,
    const float* __restrict__ c1g, const float* __restrict__ c0g,
    float* __restrict__ out) {
  const int b = blockIdx.y;
  __shared__ u16 Xt[64 * XT_];     // 16896 B
  __shared__ float c1s[C_], c0s[C_];
  const int tid = threadIdx.x, lane = tid & 63, w = tid >> 6;  // wave 0..7
  const int n = lane & 15, q = lane >> 4;

  if (tid < C_) { c1s[tid] = c1g[b * C_ + tid]; c0s[tid] = c0g[b * C_ + tid]; }

  // per-wave Wo fragments: af[s] = Wo_bf16[16w+n][32s+8q .. +7]  (16 VGPRs)
  s8v af[4];
#pragma unroll
  for (int s = 0; s < 4; ++s)
    af[s] = *(const s8v*)(wo_bf + (16 * w + n) * C_ + 32 * s + 8 * q);

  const float* xb = x + (size_t)b * C_ * HW_;
  float* ob = out + (size_t)b * C_ * HW_;
  const int pq = tid & 15;           // p-quad 0..15
  const int c4 = tid >> 4;           // c-quad 0..31

  float4 v[4];
  {
    const int p0 = blockIdx.x * 128;
    const float* src = xb + (size_t)(4 * c4) * HW_ + p0 + 4 * pq;
#pragma unroll
    for (int r2 = 0; r2 < 4; ++r2) v[r2] = *(const float4*)(src + (size_t)r2 * HW_);
  }

#pragma unroll 1
  for (int pt = 0; pt < 2; ++pt) {
    const int p0 = blockIdx.x * 128 + pt * 64;
    // transpose + convert + LDS write: cell = 4c x 4p per thread
    {
      float4 v0 = v[0], v1 = v[1], v2 = v[2], v3 = v[3];
      s4v s0, s1, s2, s3;
      s0[0] = (short)f2b(v0.x); s0[1] = (short)f2b(v1.x); s0[2] = (short)f2b(v2.x); s0[3] = (short)f2b(v3.x);
      s1[0] = (short)f2b(v0.y); s1[1] = (short)f2b(v1.y); s1[2] = (short)f2b(v2.y); s1[3] = (short)f2b(v3.y);
      s2[0] = (short)f2b(v0.z); s2[1] = (short)f2b(v1.z); s2[2] = (short)f2b(v2.z); s2[3] = (short)f2b(v3.z);
      s3[0] = (short)f2b(v0.w); s3[1] = (short)f2b(v1.w); s3[2] = (short)f2b(v2.w); s3[3] = (short)f2b(v3.w);
      *(s4v*)(&Xt[(4 * pq + 0) * XT_ + 4 * c4]) = s0;
      *(s4v*)(&Xt[(4 * pq + 1) * XT_ + 4 * c4]) = s1;
      *(s4v*)(&Xt[(4 * pq + 2) * XT_ + 4 * c4]) = s2;
      *(s4v*)(&Xt[(4 * pq + 3) * XT_ + 4 * c4]) = s3;
    }
    __syncthreads();
    if (pt < 1) {  // prefetch next tile under MFMA
      const float* src = xb + (size_t)(4 * c4) * HW_ + p0 + 64 + 4 * pq;
#pragma unroll
      for (int r2 = 0; r2 < 4; ++r2) v[r2] = *(const float4*)(src + (size_t)r2 * HW_);
    }

    f4v acc[4];
#pragma unroll
    for (int p2 = 0; p2 < 4; ++p2) acc[p2] = (f4v){0.f, 0.f, 0.f, 0.f};
#pragma unroll
    for (int s = 0; s < 4; ++s) {
#pragma unroll
      for (int p2 = 0; p2 < 4; ++p2) {
        s8v bfr = *(const s8v*)(&Xt[(16 * p2 + n) * XT_ + 32 * s + 8 * q]);
        acc[p2] = __builtin_amdgcn_mfma_f32_16x16x32_bf16(af[s], bfr, acc[p2], 0, 0, 0);
      }
    }

#pragma unroll
    for (int p2 = 0; p2 < 4; ++p2)
#pragma unroll
      for (int r = 0; r < 4; ++r) {
        int o = 16 * w + 4 * q + r;
        size_t idx = (size_t)o * HW_ + p0 + 16 * p2 + n;
        ob[idx] = xb[idx] + c1s[o] * acc[p2][r] + c0s[o];
      }
    __syncthreads();
  }
}

extern "C" void kernel_launch(void* const* d_in, const int* in_sizes, int n_in,
                              void* d_out, int out_size, void* d_ws, size_t ws_size,
                              hipStream_t stream) {
  (void)in_sizes; (void)n_in; (void)out_size; (void)ws_size;
  const float* x     = (const float*)d_in[0];
  const float* Wsa   = (const float*)d_in[1];
  const float* bsa   = (const float*)d_in[2];
  const float* Wr    = (const float*)d_in[3];
  const float* br    = (const float*)d_in[4];
  const float* kn    = (const float*)d_in[5];
  const float* Wo    = (const float*)d_in[6];
  const float* bo    = (const float*)d_in[7];
  const float* alpha = (const float*)d_in[8];
  const float* sigma = (const float*)d_in[9];
  float* out = (float*)d_out;
  float* ws  = (float*)d_ws;

  float* G        = ws;            // 131072
  float* sx       = ws + 131072;   // 1024
  float* diagR    = ws + 132096;   // 1024
  float* diagSA   = ws + 133120;   // 1024
  float* colsumSA = ws + 134144;   // 1024
  float* diagO    = ws + 135168;   // 1024
  float* prv      = ws + 136192;   // 1024
  float* psav     = ws + 137216;   // 1024
  float* pov      = ws + 138240;   // 1024
  float* rel      = ws + 139264;   // 16384
  float* diagN    = ws + 155648;   // 128
  float* ksx      = ws + 155776;   // 128
  float* u        = ws + 155904;   // 128
  float* C1w      = ws + 156032;   // 1024
  float* C0w      = ws + 157056;   // 1024
  u16*   wo_bf    = (u16*)(ws + 158080);  // 16384 u16 = 8192 floats

  // d_out doubles as scratch for Gram partials until k_out overwrites it:
  float* pbuf = out;               // 64*8*16384 = 8388608 floats
  float* psx  = out + 8388608;     // 64*8*128   = 65536 floats

  k_gram<<<dim3(65, 8), 512, 0, stream>>>(x, pbuf, psx, Wsa, kn, Wo, u,
      out + (size_t)B_ * C_ * HW_, wo_bf);
  k_greduce<<<264, 128, 0, stream>>>((const f4v*)pbuf, psx, G, sx);
  k_cols<<<dim3(144, 8), 64, 0, stream>>>(G, sx, Wr, Wsa, Wo, kn, u,
      diagR, diagSA, colsumSA, diagO, prv, psav, pov, rel, diagN, ksx);
  k_asm<<<8, 128, 0, stream>>>(diagR, diagSA, colsumSA, diagO, prv, psav, pov,
      rel, diagN, ksx, br, bo, bsa, alpha, sigma, C1w, C0w);
  k_out<<<dim3(128, 8), 512, 0, stream>>>(x, wo_bf, C1w, C0w, out);
}